// Round 5
// baseline (126.197 us; speedup 1.0000x reference)
//
#include <hip/hip_runtime.h>
#include <hip/hip_cooperative_groups.h>
#include <math.h>

namespace cg = cooperative_groups;

#define NN 128
#define FF 32
#define TT 5
#define DCAP 64   // max-degree capacity (actual max deg ~45 for seed-0 graph)
#define NW 16     // waves per block (1024 threads)

__device__ __forceinline__ float sig_(float v) { return 1.f / (1.f + expf(-v)); }

// ---------------------------------------------------------------------------
// Whole GraphEncoder in ONE cooperative kernel. Block i owns node i and its
// edge set (built via ballot). Per-edge hoisted Wu@x / Wcm@x terms live in
// LDS for all 5 steps. The only cross-block data is M (double-buffered in
// d_ws); one grid.sync() per step boundary (4 total). No atomics anywhere.
// Lane map per edge-wave: f = l>>1 (output row), h = l&1 (16-col half).
// ---------------------------------------------------------------------------
__global__ __launch_bounds__(1024, 1) void k_all(
        const int* __restrict__ adj, const float* __restrict__ x,
        const float* __restrict__ Wu, const float* __restrict__ Wcm,
        const float* __restrict__ Uu, const float* __restrict__ Ucm,
        const float* __restrict__ bu, const float* __restrict__ bcm,
        const float* __restrict__ Unf, const float* __restrict__ Unm,
        float* __restrict__ M0, float* __restrict__ M1,
        float* __restrict__ out) {
    cg::grid_group grid = cg::this_grid();
    const int i = blockIdx.x;
    const int t = threadIdx.x;
    const int w = t >> 6, l = t & 63;
    const int f = l >> 1, h = l & 1, ll = l & 31;

    __shared__ int   nbr_s[DCAP];
    __shared__ int   wcnt[2];
    __shared__ float xs[FF], bu_s[FF], bcm_s[FF];
    __shared__ float sin_s[FF], rout_s[FF];
    __shared__ float sp[32][FF];
    __shared__ float wux[DCAP][FF], wcmx[DCAP][FF];
    __shared__ float zs[DCAP][FF], pvl[DCAP][FF], rml[DCAP][FF];

    // ---- neighbor list via ballot (waves 0,1 test adjacency row i) ----
    const bool pred = (t < NN) && (adj[i * NN + t] != 0);
    const unsigned long long mask = __ballot(pred);
    if (w < 2 && l == 0) wcnt[w] = __popcll(mask);
    if (t < FF) { bu_s[t] = bu[t]; bcm_s[t] = bcm[t]; }
    else if (t < 2 * FF) xs[t - FF] = x[i * FF + (t - FF)];
    __syncthreads();
    if (pred) {
        const int base = (w == 1) ? wcnt[0] : 0;
        nbr_s[base + __popcll(mask & ((1ull << (unsigned)l) - 1ull))] = t;
    }
    __syncthreads();
    const int dg = wcnt[0] + wcnt[1];

    // ---- step 0 (messages == 0): hoist Wu@x, Wcm@x; M0 = sig*tanh ----
    for (int s = w; s < dg; s += NW) {
        const int j = nbr_s[s];
        const size_t e = (size_t)i * NN + j;
        const float4* __restrict__ wr = (const float4*)(Wu + (e * FF + f) * FF + h * 16);
        const float4* __restrict__ cr = (const float4*)(Wcm + (e * FF + f) * FF + h * 16);
        float a0 = 0.f, a1 = 0.f;
#pragma unroll
        for (int q = 0; q < 4; ++q) {
            const float4 w4 = wr[q], c4 = cr[q];
            const int g0 = h * 16 + q * 4;
            a0 += w4.x * xs[g0 + 0] + w4.y * xs[g0 + 1] + w4.z * xs[g0 + 2] + w4.w * xs[g0 + 3];
            a1 += c4.x * xs[g0 + 0] + c4.y * xs[g0 + 1] + c4.z * xs[g0 + 2] + c4.w * xs[g0 + 3];
        }
        a0 += __shfl_xor(a0, 1);
        a1 += __shfl_xor(a1, 1);
        if (h == 0) {
            wux[s][f] = a0;
            wcmx[s][f] = a1;
            M0[e * FF + f] = sig_(a0 + bu_s[f]) * tanhf(a1 + bcm_s[f]);
        }
    }
    grid.sync();

    const float* Mi = M0;
    float* Mo = M1;
    for (int st = 1; st < TT; ++st) {
        // ---- SIN[i,f] = sum over in-edges (k,i): 32 partial groups ----
        {
            const int g = t >> 5;
            float s = 0.f;
            for (int sl = g; sl < dg; sl += 32)
                s += Mi[((size_t)nbr_s[sl] * NN + i) * FF + ll];
            sp[g][ll] = s;
        }
        __syncthreads();
        if (t < FF) {
            float s = 0.f;
#pragma unroll
            for (int g = 0; g < 32; ++g) s += sp[g][t];
            sin_s[t] = s;
        }
        __syncthreads();

        // ---- pass A: per out-edge z, r, rm; keep in LDS ----
        for (int s = w; s < dg; s += NW) {
            const int j = nbr_s[s];
            const size_t e = (size_t)i * NN + j;
            const float mval = Mi[e * FF + ll];
            const float pval = sin_s[ll] - Mi[((size_t)j * NN + i) * FF + ll];
            const float4* __restrict__ ur = (const float4*)(Uu + (e * FF + f) * FF + h * 16);
            float aP = 0.f, aM = 0.f;
#pragma unroll
            for (int q = 0; q < 4; ++q) {
                const float4 u4 = ur[q];
                const int g0 = h * 16 + q * 4;
                float pv, mv;
                pv = __shfl(pval, g0 + 0); mv = __shfl(mval, g0 + 0); aP += u4.x * pv; aM += u4.x * mv;
                pv = __shfl(pval, g0 + 1); mv = __shfl(mval, g0 + 1); aP += u4.y * pv; aM += u4.y * mv;
                pv = __shfl(pval, g0 + 2); mv = __shfl(mval, g0 + 2); aP += u4.z * pv; aM += u4.z * mv;
                pv = __shfl(pval, g0 + 3); mv = __shfl(mval, g0 + 3); aP += u4.w * pv; aM += u4.w * mv;
            }
            aP += __shfl_xor(aP, 1);
            aM += __shfl_xor(aM, 1);
            const float m_f = __shfl(mval, f);
            const float p_f = __shfl(pval, f);
            if (h == 0) {
                const float wx = wux[s][f] + bu_s[f];
                const float zg = sig_(wx + aP);
                const float r  = sig_(wx + aM);
                zs[s][f] = zg;
                pvl[s][f] = p_f;
                rml[s][f] = r * m_f;
            }
        }
        __syncthreads();

        // ---- block-local ROUT ----
        {
            const int g = t >> 5;
            float s = 0.f;
            for (int sl = g; sl < dg; sl += 32) s += rml[sl][ll];
            sp[g][ll] = s;
        }
        __syncthreads();
        if (t < FF) {
            float s = 0.f;
#pragma unroll
            for (int g = 0; g < 32; ++g) s += sp[g][t];
            rout_s[t] = s;
        }
        __syncthreads();

        // ---- pass B: reset_sum, cm, GRU compose ----
        for (int s = w; s < dg; s += NW) {
            const int j = nbr_s[s];
            const size_t e = (size_t)i * NN + j;
            const float rbv = rout_s[ll] - rml[s][ll];
            const float4* __restrict__ ur = (const float4*)(Ucm + (e * FF + f) * FF + h * 16);
            float a = 0.f;
#pragma unroll
            for (int q = 0; q < 4; ++q) {
                const float4 u4 = ur[q];
                const int g0 = h * 16 + q * 4;
                a += u4.x * __shfl(rbv, g0 + 0) + u4.y * __shfl(rbv, g0 + 1)
                   + u4.z * __shfl(rbv, g0 + 2) + u4.w * __shfl(rbv, g0 + 3);
            }
            a += __shfl_xor(a, 1);
            if (h == 0) {
                const float cmv = tanhf(wcmx[s][f] + a + bcm_s[f]);
                const float zg = zs[s][f];
                const float mnew = (1.f - zg) * pvl[s][f] + zg * cmv;
                if (st < TT - 1) Mo[e * FF + f] = mnew;
                else             pvl[s][f] = mnew;   // last step: stash for out_sum
            }
        }
        if (st < TT - 1) {
            grid.sync();
            const float* tmp = Mo; Mo = (float*)Mi; Mi = tmp;
        }
    }

    // ---- final: out_sum (block-local) + node encoding ----
    __syncthreads();
    {
        const int g = t >> 5;
        float s = 0.f;
        for (int sl = g; sl < dg; sl += 32) s += pvl[sl][ll];
        sp[g][ll] = s;
    }
    __syncthreads();
    if (t < FF) {
        float s = 0.f;
#pragma unroll
        for (int g = 0; g < 32; ++g) s += sp[g][t];
        rout_s[t] = s;   // out_sum
    }
    __syncthreads();
    if (t < 64) {
        const size_t rb = ((size_t)i * FF + f) * FF + h * 16;
        const float4* __restrict__ fr = (const float4*)(Unf + rb);
        const float4* __restrict__ mr = (const float4*)(Unm + rb);
        float a = 0.f;
#pragma unroll
        for (int q = 0; q < 4; ++q) {
            const float4 f4 = fr[q], m4 = mr[q];
            const int g0 = h * 16 + q * 4;
            a += f4.x * xs[g0 + 0] + f4.y * xs[g0 + 1] + f4.z * xs[g0 + 2] + f4.w * xs[g0 + 3];
            a += m4.x * rout_s[g0 + 0] + m4.y * rout_s[g0 + 1]
               + m4.z * rout_s[g0 + 2] + m4.w * rout_s[g0 + 3];
        }
        a += __shfl_xor(a, 1);
        if (h == 0) out[i * FF + f] = fmaxf(a, 0.f);
    }
}

extern "C" void kernel_launch(void* const* d_in, const int* in_sizes, int n_in,
                              void* d_out, int out_size, void* d_ws, size_t ws_size,
                              hipStream_t stream) {
    const float* x   = (const float*)d_in[0];
    const int*   adj = (const int*)d_in[1];
    const float* Wu  = (const float*)d_in[2];
    const float* Uu  = (const float*)d_in[3];
    const float* Wcm = (const float*)d_in[4];
    const float* Ucm = (const float*)d_in[5];
    const float* bu  = (const float*)d_in[6];
    const float* bcm = (const float*)d_in[7];
    const float* Unf = (const float*)d_in[8];
    const float* Unm = (const float*)d_in[9];
    float* out = (float*)d_out;

    const size_t EF = (size_t)NN * NN * FF;  // 524288 floats per dense [N,N,F]
    float* M0 = (float*)d_ws;
    float* M1 = M0 + EF;
    // ws use: 4 MiB. No zero-init needed: step0 writes every edge row of M0
    // before any read; non-edge rows are never read.

    void* args[] = {
        (void*)&adj, (void*)&x, (void*)&Wu, (void*)&Wcm, (void*)&Uu, (void*)&Ucm,
        (void*)&bu, (void*)&bcm, (void*)&Unf, (void*)&Unm,
        (void*)&M0, (void*)&M1, (void*)&out,
    };
    hipLaunchCooperativeKernel((const void*)k_all, dim3(NN), dim3(1024),
                               args, 0, stream);
}

// Round 6
// 46.416 us; speedup vs baseline: 2.7188x; 2.7188x over previous
//
#include <hip/hip_runtime.h>
#include <math.h>

#define NN 128
#define FF 32
#define TT 5

__device__ __forceinline__ float sig_(float v) { return 1.f / (1.f + expf(-v)); }

// acc += u4 . vec[g0..g0+3]  (vec held in vector layout: lane v has vec[v&31])
#define DOT4(acc, u4, vec, g0)                                        \
    acc += u4.x * __shfl(vec, (g0) + 0) + u4.y * __shfl(vec, (g0) + 1) \
         + u4.z * __shfl(vec, (g0) + 2) + u4.w * __shfl(vec, (g0) + 3);

// ---------------------------------------------------------------------------
// Zero the 9 small accumulators (sin1..4, rout1..4, outsum): 9*4096 floats.
// ---------------------------------------------------------------------------
__global__ void k_zero(float* __restrict__ z) {
    z[blockIdx.x * 256 + threadIdx.x] = 0.f;
}

// ---------------------------------------------------------------------------
// Iteration 0 (messages == 0). Per directed edge e=(i,j), one wave:
//   wux = Wu[e]@x_i, wcmx = Wcm[e]@x_i  (persisted for all steps)
//   M1[e] = sig(wux+bu) * tanh(wcmx+bcm)          (prev=0, reset_sum=0)
//   sin1[j] += M1[e]
//   r1 = sig(wux + Uu[e]@M1[e] + bu); RM[e] = r1*M1[e]; rout1[i] += RM[e]
// Lane map: f = l>>1 (output row), h = l&1 (16-col half); ll = l&31 (vector).
// ---------------------------------------------------------------------------
__global__ __launch_bounds__(256) void k_step0(
        const int* __restrict__ adj, const float* __restrict__ x,
        const float* __restrict__ Wu, const float* __restrict__ Wcm,
        const float* __restrict__ Uu,
        const float* __restrict__ bu, const float* __restrict__ bcm,
        float* __restrict__ WUX, float* __restrict__ WCMX,
        float* __restrict__ M1, float* __restrict__ RM,
        float* __restrict__ sin1, float* __restrict__ rout1) {
    const int e = blockIdx.x * 4 + (threadIdx.x >> 6);
    if (!adj[e]) return;
    const int l = threadIdx.x & 63;
    const int i = e >> 7, j = e & 127;
    const int f = l >> 1, h = l & 1, ll = l & 31;
    const float xv = x[i * FF + ll];
    const size_t rb = ((size_t)e * FF + f) * FF + h * 16;
    const float4* __restrict__ wr = (const float4*)(Wu + rb);
    const float4* __restrict__ cr = (const float4*)(Wcm + rb);
    float a0 = 0.f, a1 = 0.f;
#pragma unroll
    for (int q = 0; q < 4; ++q) {
        const float4 w4 = wr[q], c4 = cr[q];
        const int g0 = h * 16 + q * 4;
        DOT4(a0, w4, xv, g0)
        DOT4(a1, c4, xv, g0)
    }
    a0 += __shfl_xor(a0, 1);
    a1 += __shfl_xor(a1, 1);
    const float bu_f = bu[f], bcm_f = bcm[f];
    const float m_pair = sig_(a0 + bu_f) * tanhf(a1 + bcm_f);
    if (h == 0) {
        WUX[(size_t)e * FF + f] = a0;
        WCMX[(size_t)e * FF + f] = a1;
    }
    const float mv = __shfl(m_pair, 2 * ll);   // vector layout
    if (l < 32) {
        M1[(size_t)e * FF + ll] = mv;
        atomicAdd(&sin1[j * FF + ll], mv);
    }
    // r for iteration 1
    const float4* __restrict__ ur = (const float4*)(Uu + rb);
    float aR = 0.f;
#pragma unroll
    for (int q = 0; q < 4; ++q) {
        const float4 u4 = ur[q];
        const int g0 = h * 16 + q * 4;
        DOT4(aR, u4, mv, g0)
    }
    aR += __shfl_xor(aR, 1);
    const float rm_pair = sig_(a0 + aR + bu_f) * m_pair;
    const float rmv = __shfl(rm_pair, 2 * ll);
    if (l < 32) {
        RM[(size_t)e * FF + ll] = rmv;
        atomicAdd(&rout1[i * FF + ll], rmv);
    }
}

// ---------------------------------------------------------------------------
// Iteration t (1..4). Per edge e=(i,j), one wave:
//   prev = sin_t[i] - M_in[j,i]
//   z  = sig(WUX + Uu[e]@prev + bu)            (Uu row cached in registers)
//   rs = rout_t[i] - RM[e]
//   cm = tanh(WCMX + Ucm[e]@rs + bcm)
//   mnew = (1-z)*prev + z*cm
//   LAST:   outsum[i] += mnew
//   !LAST:  M_out[e] = mnew; sin_next[j] += mnew;
//           r' = sig(WUX + Uu[e]@mnew + bu); RM[e] = r'*mnew; rout_next[i] += .
// ---------------------------------------------------------------------------
template <int LAST>
__global__ __launch_bounds__(256) void k_step(
        const int* __restrict__ adj,
        const float* __restrict__ Uu, const float* __restrict__ Ucm,
        const float* __restrict__ bu, const float* __restrict__ bcm,
        const float* __restrict__ WUX, const float* __restrict__ WCMX,
        const float* __restrict__ M_in, float* __restrict__ M_out,
        float* __restrict__ RM,
        const float* __restrict__ sin_t, const float* __restrict__ rout_t,
        float* __restrict__ sin_next, float* __restrict__ rout_next,
        float* __restrict__ outsum) {
    const int e = blockIdx.x * 4 + (threadIdx.x >> 6);
    if (!adj[e]) return;
    const int l = threadIdx.x & 63;
    const int i = e >> 7, j = e & 127;
    const int f = l >> 1, h = l & 1, ll = l & 31;
    const size_t rb = ((size_t)e * FF + f) * FF + h * 16;

    const float prevv = sin_t[i * FF + ll] - M_in[((size_t)j * NN + i) * FF + ll];
    const float4* __restrict__ ur = (const float4*)(Uu + rb);
    const float4 u0 = ur[0], u1 = ur[1], u2 = ur[2], u3 = ur[3];
    float aP = 0.f;
    {
        const int g0 = h * 16;
        DOT4(aP, u0, prevv, g0 + 0)
        DOT4(aP, u1, prevv, g0 + 4)
        DOT4(aP, u2, prevv, g0 + 8)
        DOT4(aP, u3, prevv, g0 + 12)
    }
    aP += __shfl_xor(aP, 1);
    const float bu_f = bu[f];
    const float wux_f = WUX[(size_t)e * FF + f];
    const float z = sig_(wux_f + aP + bu_f);

    const float rsv = rout_t[i * FF + ll] - RM[(size_t)e * FF + ll];
    const float4* __restrict__ crp = (const float4*)(Ucm + rb);
    float aC = 0.f;
    {
        const int g0 = h * 16;
        DOT4(aC, crp[0], rsv, g0 + 0)
        DOT4(aC, crp[1], rsv, g0 + 4)
        DOT4(aC, crp[2], rsv, g0 + 8)
        DOT4(aC, crp[3], rsv, g0 + 12)
    }
    aC += __shfl_xor(aC, 1);
    const float cmv = tanhf(WCMX[(size_t)e * FF + f] + aC + bcm[f]);

    const float prev_f = __shfl(prevv, f);
    const float m_pair = (1.f - z) * prev_f + z * cmv;
    const float mv = __shfl(m_pair, 2 * ll);   // vector layout

    if (LAST) {
        if (l < 32) atomicAdd(&outsum[i * FF + ll], mv);
    } else {
        if (l < 32) {
            M_out[(size_t)e * FF + ll] = mv;
            atomicAdd(&sin_next[j * FF + ll], mv);
        }
        float aR = 0.f;
        {
            const int g0 = h * 16;
            DOT4(aR, u0, mv, g0 + 0)
            DOT4(aR, u1, mv, g0 + 4)
            DOT4(aR, u2, mv, g0 + 8)
            DOT4(aR, u3, mv, g0 + 12)
        }
        aR += __shfl_xor(aR, 1);
        const float rm_pair = sig_(wux_f + aR + bu_f) * m_pair;
        const float rmv = __shfl(rm_pair, 2 * ll);
        if (l < 32) {
            RM[(size_t)e * FF + ll] = rmv;
            atomicAdd(&rout_next[i * FF + ll], rmv);
        }
    }
}

// ---------------------------------------------------------------------------
// Final node encoding: relu(Unf[i]@x[i] + Unm[i]@outsum[i]). One wave/node.
// ---------------------------------------------------------------------------
__global__ void k_final(const float* __restrict__ x, const float* __restrict__ outsum,
                        const float* __restrict__ Unf, const float* __restrict__ Unm,
                        float* __restrict__ out) {
    const int i = blockIdx.x;
    const int l = threadIdx.x;
    const int f = l >> 1, h = l & 1, ll = l & 31;
    const float xv = x[i * FF + ll];
    const float ov = outsum[i * FF + ll];
    const size_t rb = ((size_t)i * FF + f) * FF + h * 16;
    const float4* __restrict__ fr = (const float4*)(Unf + rb);
    const float4* __restrict__ mr = (const float4*)(Unm + rb);
    float a = 0.f;
#pragma unroll
    for (int q = 0; q < 4; ++q) {
        const float4 f4 = fr[q], m4 = mr[q];
        const int g0 = h * 16 + q * 4;
        DOT4(a, f4, xv, g0)
        DOT4(a, m4, ov, g0)
    }
    a += __shfl_xor(a, 1);
    if (h == 0) out[i * FF + f] = fmaxf(a, 0.f);
}

extern "C" void kernel_launch(void* const* d_in, const int* in_sizes, int n_in,
                              void* d_out, int out_size, void* d_ws, size_t ws_size,
                              hipStream_t stream) {
    const float* x   = (const float*)d_in[0];
    const int*   adj = (const int*)d_in[1];
    const float* Wu  = (const float*)d_in[2];
    const float* Uu  = (const float*)d_in[3];
    const float* Wcm = (const float*)d_in[4];
    const float* Ucm = (const float*)d_in[5];
    const float* bu  = (const float*)d_in[6];
    const float* bcm = (const float*)d_in[7];
    const float* Unf = (const float*)d_in[8];
    const float* Unm = (const float*)d_in[9];
    float* out = (float*)d_out;

    const size_t EF = (size_t)NN * NN * FF;  // 524288 floats per dense [N,N,F]
    const size_t NF = (size_t)NN * FF;       // 4096
    float* p    = (float*)d_ws;
    float* MA   = p; p += EF;
    float* MB   = p; p += EF;
    float* WUX  = p; p += EF;
    float* WCMX = p; p += EF;
    float* RM   = p; p += EF;
    float* acc  = p; p += 9 * NF;            // sin1..4, rout1..4, outsum
    float* sinb[4]  = {acc, acc + NF, acc + 2 * NF, acc + 3 * NF};
    float* routb[4] = {acc + 4 * NF, acc + 5 * NF, acc + 6 * NF, acc + 7 * NF};
    float* outsum   = acc + 8 * NF;
    // ws use: 10 MiB + 144 KiB

    const int EG = (NN * NN) / 4;  // 4096 blocks, 4 edge-waves each

    k_zero<<<(9 * NF) / 256, 256, 0, stream>>>(acc);
    k_step0<<<EG, 256, 0, stream>>>(adj, x, Wu, Wcm, Uu, bu, bcm,
                                    WUX, WCMX, MA, RM, sinb[0], routb[0]);
    // t=1: read MA -> write MB ; t=2: MB->MA ; t=3: MA->MB ; t=4: read MB
    k_step<0><<<EG, 256, 0, stream>>>(adj, Uu, Ucm, bu, bcm, WUX, WCMX,
                                      MA, MB, RM, sinb[0], routb[0],
                                      sinb[1], routb[1], outsum);
    k_step<0><<<EG, 256, 0, stream>>>(adj, Uu, Ucm, bu, bcm, WUX, WCMX,
                                      MB, MA, RM, sinb[1], routb[1],
                                      sinb[2], routb[2], outsum);
    k_step<0><<<EG, 256, 0, stream>>>(adj, Uu, Ucm, bu, bcm, WUX, WCMX,
                                      MA, MB, RM, sinb[2], routb[2],
                                      sinb[3], routb[3], outsum);
    k_step<1><<<EG, 256, 0, stream>>>(adj, Uu, Ucm, bu, bcm, WUX, WCMX,
                                      MB, MA, RM, sinb[3], routb[3],
                                      nullptr, nullptr, outsum);
    k_final<<<NN, 64, 0, stream>>>(x, outsum, Unf, Unm, out);
}